// Round 9
// baseline (300.149 us; speedup 1.0000x reference)
//
#include <hip/hip_runtime.h>
#include <stdint.h>
#include <type_traits>

// ---------------- problem constants ----------------
#define CIN   256
#define COUT  256
#define HH    56
#define WW    56
#define HW    3136          // 56*56
#define BATCH 32
#define NPIX  (BATCH*HW)    // 100352 = 784 * 128 exactly
#define PH    58
#define PW    58
#define PPIX  (PH*PW)       // 3364
#define KTOT  2304          // 9 taps * 256 cin
#define BKB   64            // K-block 64 B -> 32 KB LDS double-buffer
#define NKIT  (KTOT/BKB)    // 36

#define NBIN  (HW/64*BATCH) // 1568 binarize blocks
#define NBRD  (BATCH*PH)    // 1856 border blocks

typedef int8_t  i8;
typedef int     intx4  __attribute__((ext_vector_type(4)));
typedef short   short8 __attribute__((ext_vector_type(8)));
typedef float   floatx4 __attribute__((ext_vector_type(4)));

// -------- global->LDS 16B async copy (offset arg MUST be 0: it shifts the
// LDS destination too — see IntrinsicsAMDGPU.td) ----------------------------
__device__ __forceinline__ void gload_lds16(const i8* g, void* lds_base) {
    __builtin_amdgcn_global_load_lds(
        (const __attribute__((address_space(1))) void*)g,
        (__attribute__((address_space(3))) void*)lds_base,
        16, 0, 0);
}

// ---------------------------------------------------------------------------
// Kernel 1 (fused front-end):
//   blocks [0, NBIN):            binarize + NCHW->padded-NHWC transpose
//   blocks [NBIN, NBIN+COUT):    weight prep + BN-acc zero-init
//   blocks [NBIN+COUT, +NBRD):   zero the 1-px border of xs
// ---------------------------------------------------------------------------
__global__ __launch_bounds__(256) void front(const float* __restrict__ x,
                                             const float* __restrict__ w,
                                             i8* __restrict__ xs,
                                             i8* __restrict__ wg,
                                             float* __restrict__ scale,
                                             float* __restrict__ bnsum,
                                             float* __restrict__ bnsumsq) {
    int b = blockIdx.x;
    int t = threadIdx.x;
    if (b < NBIN) {
        __shared__ int lds[64 * 65];   // [pix][cinquad 0..63], stride 65 dwords
        int p0 = (b % 49) * 64;
        int n  = b / 49;
        const float* xin = x + (size_t)n * CIN * HW;
        int pq  = t & 15;              // pixel quad (4 consecutive pixels)
        int cqg = t >> 4;              // channel-quad group 0..15
#pragma unroll
        for (int q = 0; q < 4; ++q) {
            int cbase = q * 64 + cqg * 4;
            floatx4 f[4];
#pragma unroll
            for (int r = 0; r < 4; ++r)
                f[r] = *(const floatx4*)&xin[(size_t)(cbase + r) * HW + p0 + pq * 4];
#pragma unroll
            for (int j = 0; j < 4; ++j) {
                int packed = 0;
#pragma unroll
                for (int r = 0; r < 4; ++r) {
                    float v = f[r][j];
                    int s = (v > 0.f) ? 1 : ((v < 0.f) ? -1 : 0);
                    packed |= (s & 0xff) << (8 * r);
                }
                lds[(pq * 4 + j) * 65 + q * 16 + cqg] = packed;
            }
        }
        __syncthreads();
        int ci = t & 15;               // 16-byte chunk (full 256B row)
#pragma unroll
        for (int q = 0; q < 4; ++q) {
            int pi = (t >> 4) + q * 16;
            int4 v;
            v.x = lds[pi * 65 + ci * 4 + 0];
            v.y = lds[pi * 65 + ci * 4 + 1];
            v.z = lds[pi * 65 + ci * 4 + 2];
            v.w = lds[pi * 65 + ci * 4 + 3];
            int p = p0 + pi;
            int h = p / WW, ww = p - (p / WW) * WW;
            *(int4*)&xs[((size_t)n * PPIX + (size_t)(h + 1) * PW + (ww + 1)) * CIN
                        + ci * 16] = v;
        }
    } else if (b < NBIN + COUT) {
        int o = b - NBIN;
        const float* wrow = w + (size_t)o * KTOT + (size_t)t * 9;   // OIHW
        float asum = 0.f;
#pragma unroll
        for (int tt = 0; tt < 9; ++tt) {
            float v = wrow[tt];
            asum += fabsf(v);
            wg[(size_t)o * KTOT + tt * CIN + t] = (v > 0.f) ? (i8)1 : ((v < 0.f) ? (i8)(-1) : (i8)0);
        }
        for (int off = 32; off > 0; off >>= 1) asum += __shfl_down(asum, off);
        __shared__ float red[4];
        if ((t & 63) == 0) red[t >> 6] = asum;
        __syncthreads();
        if (t == 0) {
            scale[o]   = (red[0] + red[1] + red[2] + red[3]) * (1.f / (float)KTOT);
            bnsum[o]   = 0.f;
            bnsumsq[o] = 0.f;
        }
    } else {
        int bb = b - NBIN - COUT;
        int n  = bb / PH;
        int pr = bb % PH;
        int* row = (int*)(xs + ((size_t)n * PPIX + (size_t)pr * PW) * CIN);
        if (pr == 0 || pr == PH - 1) {
            for (int idx = t; idx < PW * CIN / 4; idx += 256) row[idx] = 0;
        } else {
            if (t < 64)       row[t] = 0;                                   // col 0
            else if (t < 128) row[(PW - 1) * (CIN / 4) + t - 64] = 0;       // col 57
        }
    }
}

// ---------------------------------------------------------------------------
// Kernel 2: binary conv implicit GEMM, i8 MFMA K=64, BK=64B, 32 KB LDS dbuf.
// R9: plain __launch_bounds__(256) — NO waves/EU minimum. R7's (256,5) and
// R8's (256,4) both capped the UNIFIED VGPR+AGPR budget (gfx950) below the
// ~114-130 this body needs (64 AGPR acc + ~50-60 arch VGPR) and spilled acc
// to scratch (R7: +105 MB traffic; R8: +19 MB). Natural allocation should
// land ~116-130 combined -> 3-4 waves/EU -> 3-4 blocks/CU (LDS allows 5).
// Why occupancy matters here: conv dur tracks hbm_bytes/1.08 TB/s across
// R0/R4/R6/R8 (2 blocks/CU) — miss-latency-throughput limited, NOT at the
// BW wall; R7's 4-blocks/CU (even spilling) pushed 1.70 TB/s.
// Swizzle (verified R7/R8): staging chunk (tid^(tid>>3))&3, read chunk
// lhi^((l15>>1)&3). R4's pair-contiguous XCD mapping kept (FETCH halved).
// [R1 counted-vmcnt graft: -17%; R3 B-from-global: -40%. No sync grafts.]
// ---------------------------------------------------------------------------
__global__ __launch_bounds__(256) void conv_gemm(const i8* __restrict__ xs,
                                                 const i8* __restrict__ wg,
                                                 short* __restrict__ y,
                                                 float* __restrict__ bnsum,
                                                 float* __restrict__ bnsumsq) {
    __shared__ __align__(16) i8 smem[32768];   // buf b: A at b*16384, B at +8192

    int tid  = threadIdx.x;
    int lane = tid & 63;
    int wv   = tid >> 6;
    int wm   = wv & 1;        // wave row (pixels)
    int wn   = wv >> 1;       // wave col (couts)
    int hb   = blockIdx.x;
    int mt   = ((hb >> 4) << 3) + (hb & 7);   // 0..783
    int nt   = (hb >> 3) & 1;                 // 0..1

    // ---- staging source pointers (chunk-swizzled within 64B row) ----
    int prow = tid >> 2;                       // row 0..63 within a 4KB gload
    int koff = ((tid ^ (tid >> 3)) & 3) * 16;  // source chunk permute
    const i8* aP[2];
    const i8* bP[2];
#pragma unroll
    for (int j = 0; j < 2; ++j) {
        int P = mt * 128 + prow + 64 * j;     // global pixel
        int n = P / HW;
        int p = P - n * HW;
        int h = p / WW;
        int w = p - h * WW;
        aP[j] = xs + ((size_t)n * PPIX + (size_t)h * PW + w) * CIN + koff;
        int o = nt * 128 + prow + 64 * j;
        bP[j] = wg + (size_t)o * KTOT + koff;
    }
    i8* aD[2][2];
    i8* bD[2][2];
#pragma unroll
    for (int b = 0; b < 2; ++b)
#pragma unroll
        for (int j = 0; j < 2; ++j) {
            aD[b][j] = smem + b * 16384 + j * 4096 + wv * 1024;
            bD[b][j] = smem + b * 16384 + 8192 + j * 4096 + wv * 1024;
        }

    // ---- fragment read pointers (buffer 0; buffer 1 = +16384) ----
    int l15 = lane & 15;
    int lhi = lane >> 4;
    int swz = (lhi ^ ((l15 >> 1) & 3)) << 4;  // physical chunk for logical lhi
    const i8* Ard = smem + (wm * 64 + l15) * BKB + swz;
    const i8* Brd = smem + 8192 + (wn * 64 + l15) * BKB + swz;

    intx4 acc[4][4];
#pragma unroll
    for (int im = 0; im < 4; ++im)
#pragma unroll
        for (int in = 0; in < 4; ++in) acc[im][in] = intx4{0, 0, 0, 0};

    // ---- prologue: stage k=0 into buffer 0 ----
#pragma unroll
    for (int j = 0; j < 2; ++j) gload_lds16(aP[j], aD[0][j]);
#pragma unroll
    for (int j = 0; j < 2; ++j) gload_lds16(bP[j], bD[0][j]);
    __syncthreads();

    auto stage = [&](auto KBC) {
        constexpr int KB  = (int)decltype(KBC)::value;
        constexpr int cur = KB & 1;
        if constexpr (KB < NKIT - 1) {
            constexpr int nb  = KB + 1;
            constexpr int nxt = nb & 1;
            constexpr int ao  = (nb / 12) * PW * CIN + (nb % 12) * 64;  // tap walk
            constexpr int bo  = nb * BKB;
#pragma unroll
            for (int j = 0; j < 2; ++j) gload_lds16(aP[j] + ao, aD[nxt][j]);
#pragma unroll
            for (int j = 0; j < 2; ++j) gload_lds16(bP[j] + bo, bD[nxt][j]);
        }
        constexpr int bufo = cur * 16384;
        intx4 af[4], bf[4];
#pragma unroll
        for (int im = 0; im < 4; ++im) af[im] = *(const intx4*)(Ard + bufo + im * 1024);
#pragma unroll
        for (int in = 0; in < 4; ++in) bf[in] = *(const intx4*)(Brd + bufo + in * 1024);
#pragma unroll
        for (int im = 0; im < 4; ++im)
#pragma unroll
            for (int in = 0; in < 4; ++in)
                acc[im][in] = __builtin_amdgcn_mfma_i32_16x16x64_i8(
                    af[im], bf[in], acc[im][in], 0, 0, 0);
        __syncthreads();
    };
#define ST(k) stage(std::integral_constant<int, k>{});
    ST(0)  ST(1)  ST(2)  ST(3)  ST(4)  ST(5)  ST(6)  ST(7)  ST(8)
    ST(9)  ST(10) ST(11) ST(12) ST(13) ST(14) ST(15) ST(16) ST(17)
    ST(18) ST(19) ST(20) ST(21) ST(22) ST(23) ST(24) ST(25) ST(26)
    ST(27) ST(28) ST(29) ST(30) ST(31) ST(32) ST(33) ST(34) ST(35)
#undef ST

    // ---- epilogue: BN stats from regs + coalesced store via LDS transpose ----
    int colBase = nt * 128 + wn * 64 + l15;            // global cout
    short* yt = (short*)smem;                          // 128 x 128 int16, 32 KB
#pragma unroll
    for (int in = 0; in < 4; ++in) {
        int o = colBase + in * 16;
        float s1 = 0.f, s2 = 0.f;
#pragma unroll
        for (int im = 0; im < 4; ++im) {
            int r0 = wm * 64 + im * 16 + lhi * 4;      // local pixel row
#pragma unroll
            for (int rg = 0; rg < 4; ++rg) {
                int vi = acc[im][in][rg];              // exact integer count
                yt[(r0 + rg) * 128 + wn * 64 + in * 16 + l15] = (short)vi;
                float v = (float)vi;
                s1 += v;
                s2 += v * v;
            }
        }
        s1 += __shfl_xor(s1, 16); s2 += __shfl_xor(s2, 16);
        s1 += __shfl_xor(s1, 32); s2 += __shfl_xor(s2, 32);
        if (lhi == 0) {
            atomicAdd(&bnsum[o], s1);
            atomicAdd(&bnsumsq[o], s2);
        }
    }
    __syncthreads();
    // coalesced NHWC stores: 16 threads x 16B = one 128-cout half-row
#pragma unroll
    for (int pass = 0; pass < 8; ++pass) {
        int p = (tid >> 4) + 16 * pass;
        int c = tid & 15;
        *(short8*)&y[(size_t)(mt * 128 + p) * COUT + nt * 128 + c * 8] =
            *(const short8*)&yt[p * 128 + c * 8];
    }
}

// ---------------------------------------------------------------------------
// Kernel 3: int16 NHWC -> fp32 NCHW transpose + affine + relu (BN coeff fold
// fused; all y loads issued up front; 4 sequential 64-ch panels via LDS).
// ---------------------------------------------------------------------------
__global__ __launch_bounds__(256) void bn_out(const short* __restrict__ y,
                                              const float* __restrict__ bnsum,
                                              const float* __restrict__ bnsumsq,
                                              const float* __restrict__ scale,
                                              const float* __restrict__ gamma,
                                              const float* __restrict__ beta,
                                              float* __restrict__ out) {
    __shared__ float lds[64 * 65];   // [pix][ch-in-panel], stride 65
    __shared__ float gs[256], cs[256];
    int p0 = blockIdx.x * 64;
    int n  = blockIdx.y;
    int t  = threadIdx.x;

    int cch = t & 7;               // 16B chunk within a 64-ch panel
    int piA = t >> 3;              // pixel 0..31
    const short* yb = y + ((size_t)n * HW + p0) * COUT;
    short8 sv[4][2];
#pragma unroll
    for (int g = 0; g < 4; ++g)
#pragma unroll
        for (int j = 0; j < 2; ++j)
            sv[g][j] = *(const short8*)&yb[(size_t)(piA + 32 * j) * COUT + g * 64 + cch * 8];

    {
        float mean = bnsum[t] * (1.f / (float)NPIX);
        float var  = fmaxf(bnsumsq[t] * (1.f / (float)NPIX) - mean * mean, 0.f);
        float sc   = scale[t];
        float inv  = rsqrtf(sc * sc * var + 1e-5f);
        float g    = gamma[t] * sc * inv;
        gs[t] = g;
        cs[t] = beta[t] - mean * g;
    }
    __syncthreads();

#pragma unroll
    for (int g = 0; g < 4; ++g) {
        int o0 = g * 64;
#pragma unroll
        for (int j = 0; j < 2; ++j) {
            int pi = piA + 32 * j;
#pragma unroll
            for (int e = 0; e < 8; ++e) {
                int ch = o0 + cch * 8 + e;
                lds[pi * 65 + cch * 8 + e] =
                    fmaxf(gs[ch] * (float)sv[g][j][e] + cs[ch], 0.f);
            }
        }
        __syncthreads();
        float* ob = out + ((size_t)n * COUT + o0) * HW + p0;
        int pq = t & 15;       // 16 float4 = 64 pixels
        int ch = t >> 4;       // 16 channels per round
#pragma unroll
        for (int r = 0; r < 4; ++r) {
            int cr = ch + 16 * r;
            floatx4 v;
#pragma unroll
            for (int e = 0; e < 4; ++e) v[e] = lds[(pq * 4 + e) * 65 + cr];
            *(floatx4*)&ob[(size_t)cr * HW + pq * 4] = v;
        }
        if (g < 3) __syncthreads();   // WAR before next panel overwrites lds
    }
}

// ---------------------------------------------------------------------------
extern "C" void kernel_launch(void* const* d_in, const int* in_sizes, int n_in,
                              void* d_out, int out_size, void* d_ws, size_t ws_size,
                              hipStream_t stream) {
    const float* x     = (const float*)d_in[0];   // [32,256,56,56]
    const float* w     = (const float*)d_in[1];   // [256,256,3,3]
    const float* gamma = (const float*)d_in[2];   // [256]
    const float* beta  = (const float*)d_in[3];   // [256]
    float* out = (float*)d_out;

    char* ws = (char*)d_ws;
    size_t off = 0;
    i8* xs = (i8*)(ws + off);    off += (size_t)BATCH * PPIX * CIN;                // 27.6 MB
    i8* wg = (i8*)(ws + off);    off += (size_t)COUT * KTOT;                       // 0.59 MB
    short* y = (short*)(ws + off); off += (size_t)NPIX * COUT * sizeof(short);     // 51.4 MB
    float* scale   = (float*)(ws + off); off += 1024;
    float* bnsum   = (float*)(ws + off); off += 1024;
    float* bnsumsq = (float*)(ws + off); off += 1024;

    hipLaunchKernelGGL(front, dim3(NBIN + COUT + NBRD), dim3(256), 0, stream,
                       x, w, xs, wg, scale, bnsum, bnsumsq);
    hipLaunchKernelGGL(conv_gemm, dim3(NPIX / 128 * 2), dim3(256), 0, stream,
                       xs, wg, y, bnsum, bnsumsq);
    hipLaunchKernelGGL(bn_out, dim3(HW / 64, BATCH), dim3(256), 0, stream,
                       y, bnsum, bnsumsq, scale, gamma, beta, out);
}

// Round 10
// 267.623 us; speedup vs baseline: 1.1215x; 1.1215x over previous
//
#include <hip/hip_runtime.h>
#include <stdint.h>
#include <type_traits>

// ---------------- problem constants ----------------
#define CIN   256
#define COUT  256
#define HH    56
#define WW    56
#define HW    3136          // 56*56
#define BATCH 32
#define NPIX  (BATCH*HW)    // 100352 = 784 * 128 exactly
#define PH    58
#define PW    58
#define PPIX  (PH*PW)       // 3364
#define KTOT  2304          // 9 taps * 256 cin
#define BKB   128           // K-block 128 B (R6 best; BK=64 arc R7-R9 refuted)
#define NKIT  (KTOT/BKB)    // 18

#define NBIN  (HW/64*BATCH) // 1568 binarize blocks
#define NBRD  (BATCH*PH)    // 1856 border blocks

typedef int8_t  i8;
typedef int     intx4  __attribute__((ext_vector_type(4)));
typedef short   short8 __attribute__((ext_vector_type(8)));
typedef float   floatx4 __attribute__((ext_vector_type(4)));

// -------- global->LDS 16B async copy (offset arg MUST be 0: it shifts the
// LDS destination too — see IntrinsicsAMDGPU.td) ----------------------------
__device__ __forceinline__ void gload_lds16(const i8* g, void* lds_base) {
    __builtin_amdgcn_global_load_lds(
        (const __attribute__((address_space(1))) void*)g,
        (__attribute__((address_space(3))) void*)lds_base,
        16, 0, 0);
}

// ---------------------------------------------------------------------------
// Kernel 1 (fused front-end):
//   blocks [0, NBIN):            binarize + NCHW->padded-NHWC transpose
//   blocks [NBIN, NBIN+COUT):    weight prep + BN-acc zero-init
//   blocks [NBIN+COUT, +NBRD):   zero the 1-px border of xs
// R10: x loads nontemporal (read-once stream; don't churn L2).
// ---------------------------------------------------------------------------
__global__ __launch_bounds__(256) void front(const float* __restrict__ x,
                                             const float* __restrict__ w,
                                             i8* __restrict__ xs,
                                             i8* __restrict__ wg,
                                             float* __restrict__ scale,
                                             float* __restrict__ bnsum,
                                             float* __restrict__ bnsumsq) {
    int b = blockIdx.x;
    int t = threadIdx.x;
    if (b < NBIN) {
        __shared__ int lds[64 * 65];   // [pix][cinquad 0..63], stride 65 dwords
        int p0 = (b % 49) * 64;
        int n  = b / 49;
        const float* xin = x + (size_t)n * CIN * HW;
        int pq  = t & 15;              // pixel quad (4 consecutive pixels)
        int cqg = t >> 4;              // channel-quad group 0..15
#pragma unroll
        for (int q = 0; q < 4; ++q) {
            int cbase = q * 64 + cqg * 4;
            floatx4 f[4];
#pragma unroll
            for (int r = 0; r < 4; ++r)
                f[r] = __builtin_nontemporal_load(
                    (const floatx4*)&xin[(size_t)(cbase + r) * HW + p0 + pq * 4]);
#pragma unroll
            for (int j = 0; j < 4; ++j) {
                int packed = 0;
#pragma unroll
                for (int r = 0; r < 4; ++r) {
                    float v = f[r][j];
                    int s = (v > 0.f) ? 1 : ((v < 0.f) ? -1 : 0);
                    packed |= (s & 0xff) << (8 * r);
                }
                lds[(pq * 4 + j) * 65 + q * 16 + cqg] = packed;
            }
        }
        __syncthreads();
        int ci = t & 15;               // 16-byte chunk (full 256B row)
#pragma unroll
        for (int q = 0; q < 4; ++q) {
            int pi = (t >> 4) + q * 16;
            int4 v;
            v.x = lds[pi * 65 + ci * 4 + 0];
            v.y = lds[pi * 65 + ci * 4 + 1];
            v.z = lds[pi * 65 + ci * 4 + 2];
            v.w = lds[pi * 65 + ci * 4 + 3];
            int p = p0 + pi;
            int h = p / WW, ww = p - (p / WW) * WW;
            *(int4*)&xs[((size_t)n * PPIX + (size_t)(h + 1) * PW + (ww + 1)) * CIN
                        + ci * 16] = v;
        }
    } else if (b < NBIN + COUT) {
        int o = b - NBIN;
        const float* wrow = w + (size_t)o * KTOT + (size_t)t * 9;   // OIHW
        float asum = 0.f;
#pragma unroll
        for (int tt = 0; tt < 9; ++tt) {
            float v = wrow[tt];
            asum += fabsf(v);
            wg[(size_t)o * KTOT + tt * CIN + t] = (v > 0.f) ? (i8)1 : ((v < 0.f) ? (i8)(-1) : (i8)0);
        }
        for (int off = 32; off > 0; off >>= 1) asum += __shfl_down(asum, off);
        __shared__ float red[4];
        if ((t & 63) == 0) red[t >> 6] = asum;
        __syncthreads();
        if (t == 0) {
            scale[o]   = (red[0] + red[1] + red[2] + red[3]) * (1.f / (float)KTOT);
            bnsum[o]   = 0.f;
            bnsumsq[o] = 0.f;
        }
    } else {
        int bb = b - NBIN - COUT;
        int n  = bb / PH;
        int pr = bb % PH;
        int* row = (int*)(xs + ((size_t)n * PPIX + (size_t)pr * PW) * CIN);
        if (pr == 0 || pr == PH - 1) {
            for (int idx = t; idx < PW * CIN / 4; idx += 256) row[idx] = 0;
        } else {
            if (t < 64)       row[t] = 0;                                   // col 0
            else if (t < 128) row[(PW - 1) * (CIN / 4) + t - 64] = 0;       // col 57
        }
    }
}

// ---------------------------------------------------------------------------
// Kernel 2: binary conv implicit GEMM — EXACT R6 body (best measured: 275 µs
// total, conv ~78 µs, FETCH 29.5 MB). BK=128, 2x32KB dbuf, one __syncthreads
// per K-iter, (256,2), pair-contiguous XCD mapping.
// Closed arcs: R1 counted-vmcnt graft -17%; R3 B-from-global -40%;
// R7-R9 BK=64 occupancy arc (spill-free R9 still lost 25 µs: extra barriers
// outweigh 3 blocks/CU). Only change vs R6: y stores nontemporal (y is
// re-read from HBM anyway — conv FETCH proves writes don't stick in LLC).
// ---------------------------------------------------------------------------
__global__ __launch_bounds__(256, 2) void conv_gemm(const i8* __restrict__ xs,
                                                    const i8* __restrict__ wg,
                                                    short* __restrict__ y,
                                                    float* __restrict__ bnsum,
                                                    float* __restrict__ bnsumsq) {
    __shared__ __align__(16) i8 smem[65536];   // buf b: As at b*32768, Bs at +16384

    int tid  = threadIdx.x;
    int lane = tid & 63;
    int wv   = tid >> 6;
    int wm   = wv & 1;        // wave row (pixels)
    int wn   = wv >> 1;       // wave col (couts)
    int hb   = blockIdx.x;
    int mt   = ((hb >> 4) << 3) + (hb & 7);   // 0..783
    int nt   = (hb >> 3) & 1;                 // 0..1

    // ---- staging source pointers (XOR-swizzled 16B chunk within 128B row) ----
    int prow = tid >> 3;
    int koff = ((tid ^ (tid >> 3)) & 7) * 16;
    const i8* aP[4];
    const i8* bP[4];
#pragma unroll
    for (int j = 0; j < 4; ++j) {
        int P = mt * 128 + prow + 32 * j;     // global pixel
        int n = P / HW;
        int p = P - n * HW;
        int h = p / WW;
        int w = p - h * WW;
        aP[j] = xs + ((size_t)n * PPIX + (size_t)h * PW + w) * CIN + koff;
        int o = nt * 128 + prow + 32 * j;
        bP[j] = wg + (size_t)o * KTOT + koff;
    }
    i8* aD[2][4];
    i8* bD[2][4];
#pragma unroll
    for (int b = 0; b < 2; ++b)
#pragma unroll
        for (int j = 0; j < 4; ++j) {
            aD[b][j] = smem + b * 32768 + j * 4096 + wv * 1024;
            bD[b][j] = smem + b * 32768 + 16384 + j * 4096 + wv * 1024;
        }

    // ---- fragment read pointers (buffer 0; buffer 1 = +32768) ----
    int l7  = lane & 7;
    int l15 = lane & 15;
    int lhi = lane >> 4;
    int sw0 = ((lhi ^ l7) << 4);              // kk=0 swizzled chunk offset
    int sw1 = sw0 ^ 0x40;                     // kk=1
    const i8* Ard0 = smem + (wm * 64 + l15) * BKB + sw0;
    const i8* Ard1 = smem + (wm * 64 + l15) * BKB + sw1;
    const i8* Brd0 = smem + 16384 + (wn * 64 + l15) * BKB + sw0;
    const i8* Brd1 = smem + 16384 + (wn * 64 + l15) * BKB + sw1;

    intx4 acc[4][4];
#pragma unroll
    for (int im = 0; im < 4; ++im)
#pragma unroll
        for (int in = 0; in < 4; ++in) acc[im][in] = intx4{0, 0, 0, 0};

    // ---- prologue: stage k=0 into buffer 0 ----
#pragma unroll
    for (int j = 0; j < 4; ++j) gload_lds16(aP[j], aD[0][j]);
#pragma unroll
    for (int j = 0; j < 4; ++j) gload_lds16(bP[j], bD[0][j]);
    __syncthreads();

    auto stage = [&](auto KBC) {
        constexpr int KB  = (int)decltype(KBC)::value;
        constexpr int cur = KB & 1;
        if constexpr (KB < NKIT - 1) {
            constexpr int nb  = KB + 1;
            constexpr int nxt = nb & 1;
            constexpr int ao  = (nb / 6) * PW * CIN + (nb % 6) * 128;  // tap row/col
            constexpr int bo  = nb * BKB;
#pragma unroll
            for (int j = 0; j < 4; ++j) gload_lds16(aP[j] + ao, aD[nxt][j]);
#pragma unroll
            for (int j = 0; j < 4; ++j) gload_lds16(bP[j] + bo, bD[nxt][j]);
        }
        constexpr int bufo = cur * 32768;
        intx4 af0[4], bf0[4], af1[4], bf1[4];
#pragma unroll
        for (int im = 0; im < 4; ++im) af0[im] = *(const intx4*)(Ard0 + bufo + im * 2048);
#pragma unroll
        for (int in = 0; in < 4; ++in) bf0[in] = *(const intx4*)(Brd0 + bufo + in * 2048);
#pragma unroll
        for (int im = 0; im < 4; ++im) af1[im] = *(const intx4*)(Ard1 + bufo + im * 2048);
#pragma unroll
        for (int in = 0; in < 4; ++in) bf1[in] = *(const intx4*)(Brd1 + bufo + in * 2048);
#pragma unroll
        for (int im = 0; im < 4; ++im)
#pragma unroll
            for (int in = 0; in < 4; ++in)
                acc[im][in] = __builtin_amdgcn_mfma_i32_16x16x64_i8(
                    af0[im], bf0[in], acc[im][in], 0, 0, 0);
#pragma unroll
        for (int im = 0; im < 4; ++im)
#pragma unroll
            for (int in = 0; in < 4; ++in)
                acc[im][in] = __builtin_amdgcn_mfma_i32_16x16x64_i8(
                    af1[im], bf1[in], acc[im][in], 0, 0, 0);
        __syncthreads();
    };
#define ST(k) stage(std::integral_constant<int, k>{});
    ST(0) ST(1) ST(2) ST(3) ST(4) ST(5) ST(6) ST(7) ST(8)
    ST(9) ST(10) ST(11) ST(12) ST(13) ST(14) ST(15) ST(16) ST(17)
#undef ST

    // ---- epilogue: BN stats from regs + coalesced store via LDS transpose ----
    int colBase = nt * 128 + wn * 64 + l15;            // global cout
    short* yt = (short*)smem;                          // 128 x 128 int16, 32 KB
#pragma unroll
    for (int in = 0; in < 4; ++in) {
        int o = colBase + in * 16;
        float s1 = 0.f, s2 = 0.f;
#pragma unroll
        for (int im = 0; im < 4; ++im) {
            int r0 = wm * 64 + im * 16 + lhi * 4;      // local pixel row
#pragma unroll
            for (int rg = 0; rg < 4; ++rg) {
                int vi = acc[im][in][rg];              // exact integer count
                yt[(r0 + rg) * 128 + wn * 64 + in * 16 + l15] = (short)vi;
                float v = (float)vi;
                s1 += v;
                s2 += v * v;
            }
        }
        s1 += __shfl_xor(s1, 16); s2 += __shfl_xor(s2, 16);
        s1 += __shfl_xor(s1, 32); s2 += __shfl_xor(s2, 32);
        if (lhi == 0) {
            atomicAdd(&bnsum[o], s1);
            atomicAdd(&bnsumsq[o], s2);
        }
    }
    __syncthreads();
    // coalesced NHWC stores: 16 threads x 16B = one 128-cout half-row
#pragma unroll
    for (int pass = 0; pass < 8; ++pass) {
        int p = (tid >> 4) + 16 * pass;
        int c = tid & 15;
        __builtin_nontemporal_store(
            *(const short8*)&yt[p * 128 + c * 8],
            (short8*)&y[(size_t)(mt * 128 + p) * COUT + nt * 128 + c * 8]);
    }
}

// ---------------------------------------------------------------------------
// Kernel 3: int16 NHWC -> fp32 NCHW transpose + affine + relu (BN coeff fold
// fused; all y loads issued up front; 4 sequential 64-ch panels via LDS).
// R10: y loads + out stores nontemporal (both are HBM streams with no reuse).
// ---------------------------------------------------------------------------
__global__ __launch_bounds__(256) void bn_out(const short* __restrict__ y,
                                              const float* __restrict__ bnsum,
                                              const float* __restrict__ bnsumsq,
                                              const float* __restrict__ scale,
                                              const float* __restrict__ gamma,
                                              const float* __restrict__ beta,
                                              float* __restrict__ out) {
    __shared__ float lds[64 * 65];   // [pix][ch-in-panel], stride 65
    __shared__ float gs[256], cs[256];
    int p0 = blockIdx.x * 64;
    int n  = blockIdx.y;
    int t  = threadIdx.x;

    int cch = t & 7;               // 16B chunk within a 64-ch panel
    int piA = t >> 3;              // pixel 0..31
    const short* yb = y + ((size_t)n * HW + p0) * COUT;
    short8 sv[4][2];
#pragma unroll
    for (int g = 0; g < 4; ++g)
#pragma unroll
        for (int j = 0; j < 2; ++j)
            sv[g][j] = __builtin_nontemporal_load(
                (const short8*)&yb[(size_t)(piA + 32 * j) * COUT + g * 64 + cch * 8]);

    {
        float mean = bnsum[t] * (1.f / (float)NPIX);
        float var  = fmaxf(bnsumsq[t] * (1.f / (float)NPIX) - mean * mean, 0.f);
        float sc   = scale[t];
        float inv  = rsqrtf(sc * sc * var + 1e-5f);
        float g    = gamma[t] * sc * inv;
        gs[t] = g;
        cs[t] = beta[t] - mean * g;
    }
    __syncthreads();

#pragma unroll
    for (int g = 0; g < 4; ++g) {
        int o0 = g * 64;
#pragma unroll
        for (int j = 0; j < 2; ++j) {
            int pi = piA + 32 * j;
#pragma unroll
            for (int e = 0; e < 8; ++e) {
                int ch = o0 + cch * 8 + e;
                lds[pi * 65 + cch * 8 + e] =
                    fmaxf(gs[ch] * (float)sv[g][j][e] + cs[ch], 0.f);
            }
        }
        __syncthreads();
        float* ob = out + ((size_t)n * COUT + o0) * HW + p0;
        int pq = t & 15;       // 16 float4 = 64 pixels
        int ch = t >> 4;       // 16 channels per round
#pragma unroll
        for (int r = 0; r < 4; ++r) {
            int cr = ch + 16 * r;
            floatx4 v;
#pragma unroll
            for (int e = 0; e < 4; ++e) v[e] = lds[(pq * 4 + e) * 65 + cr];
            __builtin_nontemporal_store(v, (floatx4*)&ob[(size_t)cr * HW + pq * 4]);
        }
        if (g < 3) __syncthreads();   // WAR before next panel overwrites lds
    }
}

// ---------------------------------------------------------------------------
extern "C" void kernel_launch(void* const* d_in, const int* in_sizes, int n_in,
                              void* d_out, int out_size, void* d_ws, size_t ws_size,
                              hipStream_t stream) {
    const float* x     = (const float*)d_in[0];   // [32,256,56,56]
    const float* w     = (const float*)d_in[1];   // [256,256,3,3]
    const float* gamma = (const float*)d_in[2];   // [256]
    const float* beta  = (const float*)d_in[3];   // [256]
    float* out = (float*)d_out;

    char* ws = (char*)d_ws;
    size_t off = 0;
    i8* xs = (i8*)(ws + off);    off += (size_t)BATCH * PPIX * CIN;                // 27.6 MB
    i8* wg = (i8*)(ws + off);    off += (size_t)COUT * KTOT;                       // 0.59 MB
    short* y = (short*)(ws + off); off += (size_t)NPIX * COUT * sizeof(short);     // 51.4 MB
    float* scale   = (float*)(ws + off); off += 1024;
    float* bnsum   = (float*)(ws + off); off += 1024;
    float* bnsumsq = (float*)(ws + off); off += 1024;

    hipLaunchKernelGGL(front, dim3(NBIN + COUT + NBRD), dim3(256), 0, stream,
                       x, w, xs, wg, scale, bnsum, bnsumsq);
    hipLaunchKernelGGL(conv_gemm, dim3(NPIX / 128 * 2), dim3(256), 0, stream,
                       xs, wg, y, bnsum, bnsumsq);
    hipLaunchKernelGGL(bn_out, dim3(HW / 64, BATCH), dim3(256), 0, stream,
                       y, bnsum, bnsumsq, scale, gamma, beta, out);
}

// Round 11
// 265.196 us; speedup vs baseline: 1.1318x; 1.0092x over previous
//
#include <hip/hip_runtime.h>
#include <stdint.h>
#include <type_traits>

// ---------------- problem constants ----------------
#define CIN   256
#define COUT  256
#define HH    56
#define WW    56
#define HW    3136          // 56*56
#define BATCH 32
#define NPIX  (BATCH*HW)    // 100352 = 784 * 128 exactly
#define PH    58
#define PW    58
#define PPIX  (PH*PW)       // 3364
#define KTOT  2304          // 9 taps * 256 cin
#define BKB   128           // K-block 128 B (R6 best; BK=64 arc R7-R9 refuted)
#define NKIT  (KTOT/BKB)    // 18

#define NBIN  (HW/64*BATCH) // 1568 binarize blocks
#define NBRD  (BATCH*PH)    // 1856 border blocks

typedef int8_t  i8;
typedef int     intx4  __attribute__((ext_vector_type(4)));
typedef short   short4v __attribute__((ext_vector_type(4)));
typedef short   short8 __attribute__((ext_vector_type(8)));
typedef float   floatx4 __attribute__((ext_vector_type(4)));

// -------- global->LDS 16B async copy (offset arg MUST be 0: it shifts the
// LDS destination too — see IntrinsicsAMDGPU.td) ----------------------------
__device__ __forceinline__ void gload_lds16(const i8* g, void* lds_base) {
    __builtin_amdgcn_global_load_lds(
        (const __attribute__((address_space(1))) void*)g,
        (__attribute__((address_space(3))) void*)lds_base,
        16, 0, 0);
}

// ---------------------------------------------------------------------------
// Kernel 1 (fused front-end):
//   blocks [0, NBIN):            binarize + NCHW->padded-NHWC transpose
//   blocks [NBIN, NBIN+COUT):    weight prep + BN-acc zero-init
//   blocks [NBIN+COUT, +NBRD):   zero the 1-px border of xs
// x loads nontemporal (read-once stream).
// ---------------------------------------------------------------------------
__global__ __launch_bounds__(256) void front(const float* __restrict__ x,
                                             const float* __restrict__ w,
                                             i8* __restrict__ xs,
                                             i8* __restrict__ wg,
                                             float* __restrict__ scale,
                                             float* __restrict__ bnsum,
                                             float* __restrict__ bnsumsq) {
    int b = blockIdx.x;
    int t = threadIdx.x;
    if (b < NBIN) {
        __shared__ int lds[64 * 65];   // [pix][cinquad 0..63], stride 65 dwords
        int p0 = (b % 49) * 64;
        int n  = b / 49;
        const float* xin = x + (size_t)n * CIN * HW;
        int pq  = t & 15;              // pixel quad (4 consecutive pixels)
        int cqg = t >> 4;              // channel-quad group 0..15
#pragma unroll
        for (int q = 0; q < 4; ++q) {
            int cbase = q * 64 + cqg * 4;
            floatx4 f[4];
#pragma unroll
            for (int r = 0; r < 4; ++r)
                f[r] = __builtin_nontemporal_load(
                    (const floatx4*)&xin[(size_t)(cbase + r) * HW + p0 + pq * 4]);
#pragma unroll
            for (int j = 0; j < 4; ++j) {
                int packed = 0;
#pragma unroll
                for (int r = 0; r < 4; ++r) {
                    float v = f[r][j];
                    int s = (v > 0.f) ? 1 : ((v < 0.f) ? -1 : 0);
                    packed |= (s & 0xff) << (8 * r);
                }
                lds[(pq * 4 + j) * 65 + q * 16 + cqg] = packed;
            }
        }
        __syncthreads();
        int ci = t & 15;               // 16-byte chunk (full 256B row)
#pragma unroll
        for (int q = 0; q < 4; ++q) {
            int pi = (t >> 4) + q * 16;
            int4 v;
            v.x = lds[pi * 65 + ci * 4 + 0];
            v.y = lds[pi * 65 + ci * 4 + 1];
            v.z = lds[pi * 65 + ci * 4 + 2];
            v.w = lds[pi * 65 + ci * 4 + 3];
            int p = p0 + pi;
            int h = p / WW, ww = p - (p / WW) * WW;
            *(int4*)&xs[((size_t)n * PPIX + (size_t)(h + 1) * PW + (ww + 1)) * CIN
                        + ci * 16] = v;
        }
    } else if (b < NBIN + COUT) {
        int o = b - NBIN;
        const float* wrow = w + (size_t)o * KTOT + (size_t)t * 9;   // OIHW
        float asum = 0.f;
#pragma unroll
        for (int tt = 0; tt < 9; ++tt) {
            float v = wrow[tt];
            asum += fabsf(v);
            wg[(size_t)o * KTOT + tt * CIN + t] = (v > 0.f) ? (i8)1 : ((v < 0.f) ? (i8)(-1) : (i8)0);
        }
        for (int off = 32; off > 0; off >>= 1) asum += __shfl_down(asum, off);
        __shared__ float red[4];
        if ((t & 63) == 0) red[t >> 6] = asum;
        __syncthreads();
        if (t == 0) {
            scale[o]   = (red[0] + red[1] + red[2] + red[3]) * (1.f / (float)KTOT);
            bnsum[o]   = 0.f;
            bnsumsq[o] = 0.f;
        }
    } else {
        int bb = b - NBIN - COUT;
        int n  = bb / PH;
        int pr = bb % PH;
        int* row = (int*)(xs + ((size_t)n * PPIX + (size_t)pr * PW) * CIN);
        if (pr == 0 || pr == PH - 1) {
            for (int idx = t; idx < PW * CIN / 4; idx += 256) row[idx] = 0;
        } else {
            if (t < 64)       row[t] = 0;                                   // col 0
            else if (t < 128) row[(PW - 1) * (CIN / 4) + t - 64] = 0;       // col 57
        }
    }
}

// ---------------------------------------------------------------------------
// Kernel 2: binary conv implicit GEMM — R6 K-loop (best measured) + R11
// epilogue change: y is now stored in NCHW [cout][NPIX] via a ch-major LDS
// tile, so bn_out becomes a pure contiguous stream (no transpose there).
//   yt = [128 ch][128 px] int16 (32 KB, reuses smem), 16B-slot XOR swizzle:
//     slot_phys = (p>>3) ^ (c & 15)   (write: b64 halves; read: b128)
//   Derivation: write phase <=4-way (uniform); read phase exactly uniform
//   (64 lanes x 16B = 8 bank-rounds = theoretical minimum).
// Store granularity to y: 256B contiguous per channel row — same as the old
// NHWC store's 256B half-rows (granularity-neutral for conv).
// K-loop unchanged: BK=128, 2x32KB dbuf, one __syncthreads/iter, (256,2),
// pair-contiguous XCD mapping (FETCH halved, verified R4).
// [Closed arcs: R1 vmcnt graft -17%; R3 B-global -40%; R7-R9 BK=64/occupancy.]
// ---------------------------------------------------------------------------
__global__ __launch_bounds__(256, 2) void conv_gemm(const i8* __restrict__ xs,
                                                    const i8* __restrict__ wg,
                                                    short* __restrict__ y,
                                                    float* __restrict__ bnsum,
                                                    float* __restrict__ bnsumsq) {
    __shared__ __align__(16) i8 smem[65536];   // buf b: As at b*32768, Bs at +16384

    int tid  = threadIdx.x;
    int lane = tid & 63;
    int wv   = tid >> 6;
    int wm   = wv & 1;        // wave row (pixels)
    int wn   = wv >> 1;       // wave col (couts)
    int hb   = blockIdx.x;
    int mt   = ((hb >> 4) << 3) + (hb & 7);   // 0..783
    int nt   = (hb >> 3) & 1;                 // 0..1

    // ---- staging source pointers (XOR-swizzled 16B chunk within 128B row) ----
    int prow = tid >> 3;
    int koff = ((tid ^ (tid >> 3)) & 7) * 16;
    const i8* aP[4];
    const i8* bP[4];
#pragma unroll
    for (int j = 0; j < 4; ++j) {
        int P = mt * 128 + prow + 32 * j;     // global pixel
        int n = P / HW;
        int p = P - n * HW;
        int h = p / WW;
        int w = p - h * WW;
        aP[j] = xs + ((size_t)n * PPIX + (size_t)h * PW + w) * CIN + koff;
        int o = nt * 128 + prow + 32 * j;
        bP[j] = wg + (size_t)o * KTOT + koff;
    }
    i8* aD[2][4];
    i8* bD[2][4];
#pragma unroll
    for (int b = 0; b < 2; ++b)
#pragma unroll
        for (int j = 0; j < 4; ++j) {
            aD[b][j] = smem + b * 32768 + j * 4096 + wv * 1024;
            bD[b][j] = smem + b * 32768 + 16384 + j * 4096 + wv * 1024;
        }

    // ---- fragment read pointers (buffer 0; buffer 1 = +32768) ----
    int l7  = lane & 7;
    int l15 = lane & 15;
    int lhi = lane >> 4;
    int sw0 = ((lhi ^ l7) << 4);              // kk=0 swizzled chunk offset
    int sw1 = sw0 ^ 0x40;                     // kk=1
    const i8* Ard0 = smem + (wm * 64 + l15) * BKB + sw0;
    const i8* Ard1 = smem + (wm * 64 + l15) * BKB + sw1;
    const i8* Brd0 = smem + 16384 + (wn * 64 + l15) * BKB + sw0;
    const i8* Brd1 = smem + 16384 + (wn * 64 + l15) * BKB + sw1;

    intx4 acc[4][4];
#pragma unroll
    for (int im = 0; im < 4; ++im)
#pragma unroll
        for (int in = 0; in < 4; ++in) acc[im][in] = intx4{0, 0, 0, 0};

    // ---- prologue: stage k=0 into buffer 0 ----
#pragma unroll
    for (int j = 0; j < 4; ++j) gload_lds16(aP[j], aD[0][j]);
#pragma unroll
    for (int j = 0; j < 4; ++j) gload_lds16(bP[j], bD[0][j]);
    __syncthreads();

    auto stage = [&](auto KBC) {
        constexpr int KB  = (int)decltype(KBC)::value;
        constexpr int cur = KB & 1;
        if constexpr (KB < NKIT - 1) {
            constexpr int nb  = KB + 1;
            constexpr int nxt = nb & 1;
            constexpr int ao  = (nb / 6) * PW * CIN + (nb % 6) * 128;  // tap row/col
            constexpr int bo  = nb * BKB;
#pragma unroll
            for (int j = 0; j < 4; ++j) gload_lds16(aP[j] + ao, aD[nxt][j]);
#pragma unroll
            for (int j = 0; j < 4; ++j) gload_lds16(bP[j] + bo, bD[nxt][j]);
        }
        constexpr int bufo = cur * 32768;
        intx4 af0[4], bf0[4], af1[4], bf1[4];
#pragma unroll
        for (int im = 0; im < 4; ++im) af0[im] = *(const intx4*)(Ard0 + bufo + im * 2048);
#pragma unroll
        for (int in = 0; in < 4; ++in) bf0[in] = *(const intx4*)(Brd0 + bufo + in * 2048);
#pragma unroll
        for (int im = 0; im < 4; ++im) af1[im] = *(const intx4*)(Ard1 + bufo + im * 2048);
#pragma unroll
        for (int in = 0; in < 4; ++in) bf1[in] = *(const intx4*)(Brd1 + bufo + in * 2048);
#pragma unroll
        for (int im = 0; im < 4; ++im)
#pragma unroll
            for (int in = 0; in < 4; ++in)
                acc[im][in] = __builtin_amdgcn_mfma_i32_16x16x64_i8(
                    af0[im], bf0[in], acc[im][in], 0, 0, 0);
#pragma unroll
        for (int im = 0; im < 4; ++im)
#pragma unroll
            for (int in = 0; in < 4; ++in)
                acc[im][in] = __builtin_amdgcn_mfma_i32_16x16x64_i8(
                    af1[im], bf1[in], acc[im][in], 0, 0, 0);
        __syncthreads();
    };
#define ST(k) stage(std::integral_constant<int, k>{});
    ST(0) ST(1) ST(2) ST(3) ST(4) ST(5) ST(6) ST(7) ST(8)
    ST(9) ST(10) ST(11) ST(12) ST(13) ST(14) ST(15) ST(16) ST(17)
#undef ST

    // ---- epilogue: BN stats + ch-major LDS tile -> NCHW y stores ----
    // yt[c][p]: addr = c*256 + ((p>>3)^(c&15))*16 + (p&7)*2
    i8* ytb = smem;                                     // 32 KB
    int colBase = nt * 128 + wn * 64 + l15;             // global cout
#pragma unroll
    for (int in = 0; in < 4; ++in) {
        int cl = wn * 64 + in * 16 + l15;               // local ch
        int o  = colBase + in * 16;
        float s1 = 0.f, s2 = 0.f;
#pragma unroll
        for (int im = 0; im < 4; ++im) {
            short4v pk;
#pragma unroll
            for (int rg = 0; rg < 4; ++rg) {
                int vi = acc[im][in][rg];              // exact integer count
                pk[rg] = (short)vi;
                float v = (float)vi;
                s1 += v;
                s2 += v * v;
            }
            int p3 = 8 * wm + 2 * im + (lhi >> 1);     // (p_base)>>3
            *(short4v*)(ytb + cl * 256 + ((p3 ^ (cl & 15)) * 16) + (lhi & 1) * 8) = pk;
        }
        s1 += __shfl_xor(s1, 16); s2 += __shfl_xor(s2, 16);
        s1 += __shfl_xor(s1, 32); s2 += __shfl_xor(s2, 32);
        if (lhi == 0) {
            atomicAdd(&bnsum[o], s1);
            atomicAdd(&bnsumsq[o], s2);
        }
    }
    __syncthreads();
    // NCHW stores: per pass, 16 lanes x 16B = one channel's 128 px (256B)
#pragma unroll
    for (int pass = 0; pass < 8; ++pass) {
        int chl = (tid >> 4) + 16 * pass;              // local ch 0..127
        int l   = tid & 15;                            // px slot 0..15
        short8 v = *(const short8*)(ytb + chl * 256 + ((l ^ (chl & 15)) * 16));
        __builtin_nontemporal_store(v,
            (short8*)&y[(size_t)(nt * 128 + chl) * NPIX + (size_t)mt * 128 + 8 * l]);
    }
}

// ---------------------------------------------------------------------------
// Kernel 3 (R11): y is NCHW now — bn_out is a PURE STREAM: per block (c, n),
// read 3136 contiguous int16, affine+relu, write 3136 contiguous fp32.
// No LDS, no barriers. 512B/wave reads, 1KB/wave writes, nontemporal both.
// ---------------------------------------------------------------------------
__global__ __launch_bounds__(256) void bn_out(const short* __restrict__ y,
                                              const float* __restrict__ bnsum,
                                              const float* __restrict__ bnsumsq,
                                              const float* __restrict__ scale,
                                              const float* __restrict__ gamma,
                                              const float* __restrict__ beta,
                                              float* __restrict__ out) {
    int c = blockIdx.x;            // cout 0..255
    int n = blockIdx.y;            // batch 0..31
    int t = threadIdx.x;

    float mean = bnsum[c] * (1.f / (float)NPIX);
    float var  = fmaxf(bnsumsq[c] * (1.f / (float)NPIX) - mean * mean, 0.f);
    float sc   = scale[c];
    float inv  = rsqrtf(sc * sc * var + 1e-5f);
    float g    = gamma[c] * sc * inv;
    float cc   = beta[c] - mean * g;

    const short4v* yb = (const short4v*)(y + (size_t)c * NPIX + (size_t)n * HW);
    floatx4* ob = (floatx4*)(out + ((size_t)n * COUT + c) * HW);
    for (int i = t; i < HW / 4; i += 256) {            // 784 float4s
        short4v s = __builtin_nontemporal_load(&yb[i]);
        floatx4 v;
#pragma unroll
        for (int e = 0; e < 4; ++e) v[e] = fmaxf(g * (float)s[e] + cc, 0.f);
        __builtin_nontemporal_store(v, &ob[i]);
    }
}

// ---------------------------------------------------------------------------
extern "C" void kernel_launch(void* const* d_in, const int* in_sizes, int n_in,
                              void* d_out, int out_size, void* d_ws, size_t ws_size,
                              hipStream_t stream) {
    const float* x     = (const float*)d_in[0];   // [32,256,56,56]
    const float* w     = (const float*)d_in[1];   // [256,256,3,3]
    const float* gamma = (const float*)d_in[2];   // [256]
    const float* beta  = (const float*)d_in[3];   // [256]
    float* out = (float*)d_out;

    char* ws = (char*)d_ws;
    size_t off = 0;
    i8* xs = (i8*)(ws + off);    off += (size_t)BATCH * PPIX * CIN;                // 27.6 MB
    i8* wg = (i8*)(ws + off);    off += (size_t)COUT * KTOT;                       // 0.59 MB
    short* y = (short*)(ws + off); off += (size_t)NPIX * COUT * sizeof(short);     // 51.4 MB (NCHW: [cout][NPIX])
    float* scale   = (float*)(ws + off); off += 1024;
    float* bnsum   = (float*)(ws + off); off += 1024;
    float* bnsumsq = (float*)(ws + off); off += 1024;

    hipLaunchKernelGGL(front, dim3(NBIN + COUT + NBRD), dim3(256), 0, stream,
                       x, w, xs, wg, scale, bnsum, bnsumsq);
    hipLaunchKernelGGL(conv_gemm, dim3(NPIX / 128 * 2), dim3(256), 0, stream,
                       xs, wg, y, bnsum, bnsumsq);
    hipLaunchKernelGGL(bn_out, dim3(COUT, BATCH), dim3(256), 0, stream,
                       y, bnsum, bnsumsq, scale, gamma, beta, out);
}